// Round 5
// baseline (655.816 us; speedup 1.0000x reference)
//
#include <hip/hip_runtime.h>

#define HH 512
#define WW 512
#define NPIX (HH * WW)          // 262144
#define NIMG 16
#define KPTS 1024
#define NWORDS (NPIX / 64)      // 4096 u64 mask words per image

// ---------------------------------------------------------------------------
// Kernel 1: binarize + uniform LBP (P=8,R=1) + ballot-pack mask bits
// ---------------------------------------------------------------------------
__global__ void lbp_kernel(const float* __restrict__ mo,
                           const float* __restrict__ lb,
                           unsigned long long* __restrict__ maskbits) {
#pragma clang fp contract(off)
    int m = blockIdx.y;                    // image 0..15: even=pred, odd=mask
    int pix = blockIdx.x * blockDim.x + threadIdx.x;   // 0..262143
    int r = pix >> 9, c = pix & 511;
    int sample = m >> 1;
    const float* img = (m & 1) ? (lb + sample * NPIX) : (mo + sample * NPIX);
    float thr = (m & 1) ? 0.5f : 0.0f;     // sigmoid(x)>0.5 <=> x>0

    float center = img[pix] > thr ? 1.0f : 0.0f;

    const float A = 0.70710678f;           // np.round(sin/cos, 8)
    const float drs[8] = {0.f, -A, -1.f, -A, 0.f,  A, 1.f, A};
    const float dcs[8] = {1.f,  A,  0.f, -A, -1.f, -A, 0.f, A};

    unsigned bb = 0u;
#pragma unroll
    for (int k = 0; k < 8; k++) {
        float rr = (float)r + drs[k];
        float cc = (float)c + dcs[k];
        float r0 = floorf(rr), c0 = floorf(cc);
        float fr = rr - r0,   fc = cc - c0;
        int r0i = (int)r0; r0i = max(0, min(HH - 1, r0i));
        int c0i = (int)c0; c0i = max(0, min(WW - 1, c0i));
        int r1i = min(HH - 1, r0i + 1);
        int c1i = min(WW - 1, c0i + 1);
        float g00 = img[r0i * WW + c0i] > thr ? 1.0f : 0.0f;
        float g01 = img[r0i * WW + c1i] > thr ? 1.0f : 0.0f;
        float g10 = img[r1i * WW + c0i] > thr ? 1.0f : 0.0f;
        float g11 = img[r1i * WW + c1i] > thr ? 1.0f : 0.0f;
        float s1 = (1.0f - fc) * g00 + fc * g01;
        float s2 = (1.0f - fc) * g10 + fc * g11;
        float smp = (1.0f - fr) * s1 + fr * s2;
        if (smp - center >= 0.0f) bb |= (1u << k);
    }
    unsigned rol = ((bb << 1) | (bb >> 7)) & 0xFFu;
    int changes = __popc(bb ^ rol);
    int s = __popc(bb);
    bool maskbit = (changes <= 2) && (s < 5);   // lbp < THR(=5)

    unsigned long long w = __ballot(maskbit);
    if ((threadIdx.x & 63) == 0)
        maskbits[m * NWORDS + (pix >> 6)] = w;
}

// ---------------------------------------------------------------------------
// Kernel 2: stable row-major compaction to K=1024 packed points per image
// pts entry: (r<<16)|c ; zero-padded. Shfl scan + uniform early-exit once
// K points are found (random inputs -> chunk 0 already has ~2x K).
// ---------------------------------------------------------------------------
__global__ void select_kernel(const unsigned long long* __restrict__ maskbits,
                              unsigned* __restrict__ ptsG) {
    __shared__ unsigned swv[4];
    int m = blockIdx.x, tid = threadIdx.x;
    int lane = tid & 63, wid = tid >> 6;

    for (int i = tid; i < KPTS; i += 256) ptsG[m * KPTS + i] = 0u;
    __syncthreads();

    unsigned running = 0;
    for (int ch = 0; ch < 16; ch++) {
        int w = ch * 256 + tid;
        unsigned long long word = maskbits[m * NWORDS + w];
        unsigned cnt = (unsigned)__popcll(word);

        unsigned x = cnt;                    // intra-wave inclusive scan
#pragma unroll
        for (int d = 1; d < 64; d <<= 1) {
            unsigned y = (unsigned)__shfl_up((int)x, d, 64);
            x += (lane >= d) ? y : 0u;
        }
        if (lane == 63) swv[wid] = x;
        __syncthreads();
        unsigned woff = 0, total = 0;
#pragma unroll
        for (int ww = 0; ww < 4; ww++) {
            unsigned t = swv[ww];
            total += t;
            woff += (ww < wid) ? t : 0u;
        }
        unsigned rank = running + woff + x - cnt;   // exclusive prefix
        while (word) {
            int b = __builtin_ctzll(word);
            word &= word - 1;
            if (rank < (unsigned)KPTS) {
                unsigned p = (unsigned)(w * 64 + b);
                unsigned rr = p >> 9, cc = p & 511u;
                ptsG[m * KPTS + rank] = (rr << 16) | cc;
            }
            rank++;
        }
        running += total;
        if (running >= (unsigned)KPTS) break;   // uniform -> safe
        __syncthreads();   // protect swv before next chunk
    }
}

// ---------------------------------------------------------------------------
// Kernel 3 (phase 1): single-wave Prim per image, RECORD-ONLY, ZERO LDS.
// key = (d2<<10)|idx : unsigned-min == argmin w/ first-index ties (d2 exact
// int < 2^19); in-tree key = 0xFFFFFFFF (signed -1 so update '<' never wins).
// pj comes from the register file (SEL16 + readlane), not LDS.
// ---------------------------------------------------------------------------
typedef short v2s __attribute__((ext_vector_type(2)));

__device__ __forceinline__ int dist2_packed(unsigned a, unsigned b) {
#if __has_builtin(__builtin_amdgcn_sdot2)
    v2s d = __builtin_bit_cast(v2s, a) - __builtin_bit_cast(v2s, b);
    return __builtin_amdgcn_sdot2(d, d, 0, false);
#else
    int dr = (int)(a >> 16) - (int)(b >> 16);
    int dc = (int)(a & 0xFFFFu) - (int)(b & 0xFFFFu);
    return __mul24(dr, dr) + __mul24(dc, dc);
#endif
}

template <int CTRL>
__device__ __forceinline__ unsigned umin_dpp(unsigned x) {
    unsigned o = (unsigned)__builtin_amdgcn_update_dpp((int)x, (int)x, CTRL,
                                                       0xf, 0xf, false);
    return o < x ? o : x;
}

__device__ __forceinline__ unsigned umin3(unsigned a, unsigned b, unsigned c) {
    unsigned t = a < b ? a : b;          // fuses to v_min3_u32
    return t < c ? t : c;
}

#define INLANE_MIN(res, K) do {                                           \
    unsigned _m0 = umin3(K[0], K[1], K[2]);                               \
    unsigned _m1 = umin3(K[3], K[4], K[5]);                               \
    unsigned _m2 = umin3(K[6], K[7], K[8]);                               \
    unsigned _m3 = umin3(K[9], K[10], K[11]);                             \
    unsigned _m4 = umin3(K[12], K[13], K[14]);                            \
    unsigned _ra = umin3(_m0, _m1, _m2);                                  \
    unsigned _rb = umin3(_m3, _m4, K[15]);                                \
    res = _ra < _rb ? _ra : _rb;                                          \
} while (0)

#define SEL16(res, arr) do {                                              \
    unsigned a0 = b0 ? arr[1]  : arr[0];                                  \
    unsigned a1 = b0 ? arr[3]  : arr[2];                                  \
    unsigned a2 = b0 ? arr[5]  : arr[4];                                  \
    unsigned a3 = b0 ? arr[7]  : arr[6];                                  \
    unsigned a4 = b0 ? arr[9]  : arr[8];                                  \
    unsigned a5 = b0 ? arr[11] : arr[10];                                 \
    unsigned a6 = b0 ? arr[13] : arr[12];                                 \
    unsigned a7 = b0 ? arr[15] : arr[14];                                 \
    unsigned c0 = b1 ? a1 : a0;                                           \
    unsigned c1 = b1 ? a3 : a2;                                           \
    unsigned c2 = b1 ? a5 : a4;                                           \
    unsigned c3 = b1 ? a7 : a6;                                           \
    unsigned e0 = b2 ? c1 : c0;                                           \
    unsigned e1 = b2 ? c3 : c2;                                           \
    res = b3 ? e1 : e0;                                                   \
} while (0)

__global__ __launch_bounds__(64, 1) void mst_kernel(const unsigned* __restrict__ ptsG,
                                                    unsigned* __restrict__ edgesG) {
    int lane = threadIdx.x;          // 0..63
    int m = blockIdx.x;

    unsigned key[16], pay[16], idxc[16];
    unsigned p0 = ptsG[m * KPTS];    // self point 0 (uniform)

#pragma unroll
    for (int s = 0; s < 16; s++) {
        unsigned p = ptsG[m * KPTS + s * 64 + lane];
        pay[s] = p;                          // (r<<16)|c
        idxc[s] = (unsigned)(s * 64 + lane);
        int d2 = dist2_packed(p, p0);
        key[s] = ((unsigned)d2 << 10) | idxc[s];
    }
    if (lane == 0) key[0] = 0xFFFFFFFFu;     // in_tree[0] = True

    unsigned* eout = edgesG + m * KPTS;
    unsigned rk;
    INLANE_MIN(rk, key);

    for (int it = 0; it < KPTS - 1; it++) {
        // ---- wave-64 min: 4 DPP row-folds + 4 readlane + scalar min ----
        rk = umin_dpp<0x111>(rk);   // row_shr:1
        rk = umin_dpp<0x112>(rk);   // row_shr:2
        rk = umin_dpp<0x114>(rk);   // row_shr:4
        rk = umin_dpp<0x118>(rk);   // row_shr:8 -> lane15 of each 16-row
        unsigned q0 = (unsigned)__builtin_amdgcn_readlane((int)rk, 15);
        unsigned q1 = (unsigned)__builtin_amdgcn_readlane((int)rk, 31);
        unsigned q2 = (unsigned)__builtin_amdgcn_readlane((int)rk, 47);
        unsigned q3 = (unsigned)__builtin_amdgcn_readlane((int)rk, 63);
        unsigned wa = q0 < q1 ? q0 : q1;
        unsigned wb = q2 < q3 ? q2 : q3;
        unsigned wk = wa < wb ? wa : wb;     // scalar, uniform

        unsigned j = wk & 1023u;
        int wslot = (int)(j >> 6);
        int wlane = (int)(j & 63u);

        if (lane == 0) eout[it] = wk;        // record edge (fire-and-forget)

        // ---- pj from the register file: SEL16 tree + readlane ----
        bool b0 = (wslot & 1) != 0, b1 = (wslot & 2) != 0;
        bool b2 = (wslot & 4) != 0, b3 = (wslot & 8) != 0;
        unsigned selPay;
        SEL16(selPay, pay);
        unsigned pjp = (unsigned)__builtin_amdgcn_readlane((int)selPay, wlane);
        v2s pj2 = __builtin_bit_cast(v2s, pjp);

        bool hit = (lane == wlane);

        // ---- decrease-key + remove j (branchless) ----
#pragma unroll
        for (int s = 0; s < 16; s++) {
            v2s d = __builtin_bit_cast(v2s, pay[s]) - pj2;
#if __has_builtin(__builtin_amdgcn_sdot2)
            int d2 = __builtin_amdgcn_sdot2(d, d, 0, false);
#else
            int d2 = (int)d.x * d.x + (int)d.y * d.y;
#endif
            unsigned nk = ((unsigned)d2 << 10) | idxc[s];
            key[s] = ((int)nk < (int)key[s]) ? nk : key[s];
            key[s] = (hit && (wslot == s)) ? 0xFFFFFFFFu : key[s];
        }
        INLANE_MIN(rk, key);                 // next iteration's per-lane min
    }
}

// ---------------------------------------------------------------------------
// Kernel 4 (phase 2): recover src per edge + per-edge (Dp-Dm)^2.
// src[j] = earliest-extracted v with d2(v,j)==d2p (exact-int match) —
// provably identical to the reference's strict-'<' update history.
// ---------------------------------------------------------------------------
__global__ void recover_kernel(const unsigned* __restrict__ ptsG,
                               const unsigned* __restrict__ edgesG,
                               float* __restrict__ contrib) {
    __shared__ unsigned sS[KPTS];
    __shared__ unsigned sO[KPTS];
    __shared__ unsigned short sT[KPTS];   // extraction time + 1 (0 = root)
    int g = blockIdx.x, m = blockIdx.y;
    int tid = threadIdx.x;
    int partner = m ^ 1;

    for (int i = tid; i < KPTS; i += 256) {
        sS[i] = ptsG[m * KPTS + i];
        sO[i] = ptsG[partner * KPTS + i];
    }
    for (int e = tid; e < KPTS - 1; e += 256) {
        unsigned wkk = edgesG[m * KPTS + e];
        sT[wkk & 1023u] = (unsigned short)(e + 1);
    }
    if (tid == 0) sT[0] = 0;
    __syncthreads();

    int lane = tid & 63, w = tid >> 6;
    for (int k = 0; k < 16; k++) {
        int e = g * 64 + w * 16 + k;
        if (e >= KPTS - 1) break;            // only e=1023 (g=15,w=3,k=15)
        unsigned wk = edgesG[m * KPTS + e];
        unsigned j = wk & 1023u;
        unsigned d2p = wk >> 10;
        unsigned pj = sS[j];
        unsigned te1 = (unsigned)(e + 1);

        unsigned best = 0xFFFFFFFFu;
#pragma unroll
        for (int i = 0; i < 16; i++) {
            int v = i * 64 + lane;
            unsigned pv = sS[v];
            int d2 = dist2_packed(pv, pj);
            unsigned tv1 = (unsigned)sT[v];
            bool qual = ((unsigned)d2 == d2p) && (tv1 < te1);
            unsigned cand = qual ? ((tv1 << 10) | (unsigned)v) : 0xFFFFFFFFu;
            best = cand < best ? cand : best;
        }
#pragma unroll
        for (int dd = 32; dd; dd >>= 1) {
            unsigned o = (unsigned)__shfl_xor((int)best, dd, 64);
            best = o < best ? o : best;
        }
        unsigned vsrc = best & 1023u;
        if (lane == 0) {
            unsigned oj = sO[j], os = sO[vsrc];
            float Dp = __fsqrt_rn((float)d2p);
            float Dm = __fsqrt_rn((float)dist2_packed(oj, os));
            float diff = Dp - Dm;
            contrib[m * (KPTS - 1) + e] = diff * diff;
        }
    }
}

// ---------------------------------------------------------------------------
// Kernel 5: per-image f64 sum (extraction order, deterministic) -> loss
// ---------------------------------------------------------------------------
__global__ void final_kernel(const float* __restrict__ contrib,
                             float* __restrict__ out) {
    __shared__ double part[NIMG];
    int t = threadIdx.x;
    if (t < NIMG) {
        double s = 0.0;
        for (int e = 0; e < KPTS - 1; e++)
            s += (double)contrib[t * (KPTS - 1) + e];
        part[t] = sqrt(s);
    }
    __syncthreads();
    if (t == 0) {
        double tot = 0.0;
        for (int i = 0; i < NIMG; i++) tot += part[i];
        out[0] = (float)(0.1 * tot / 8.0);
    }
}

// ---------------------------------------------------------------------------
// ws layout:
//   [0,512K)     maskbits (lbp->select), then DEAD:
//   [0,64K)      edgesG   (mst->recover)   — overlaps dead maskbits
//   [64K,128K)   contrib  (recover->final) — overlaps dead maskbits
//   [512K,576K)  ptsG     (select->mst/recover)
// ---------------------------------------------------------------------------
extern "C" void kernel_launch(void* const* d_in, const int* in_sizes, int n_in,
                              void* d_out, int out_size, void* d_ws, size_t ws_size,
                              hipStream_t stream) {
    const float* mo = (const float*)d_in[1];   // model_output
    const float* lb = (const float*)d_in[2];   // labels

    unsigned long long* maskbits = (unsigned long long*)d_ws;
    unsigned* edgesG = (unsigned*)d_ws;
    float* contrib = (float*)((char*)d_ws + (size_t)64 * 1024);
    unsigned* ptsG = (unsigned*)((char*)d_ws + (size_t)NIMG * NWORDS * 8);
    float* out = (float*)d_out;

    lbp_kernel<<<dim3(NPIX / 256, NIMG), 256, 0, stream>>>(mo, lb, maskbits);
    select_kernel<<<NIMG, 256, 0, stream>>>(maskbits, ptsG);
    mst_kernel<<<NIMG, 64, 0, stream>>>(ptsG, edgesG);
    recover_kernel<<<dim3(16, NIMG), 256, 0, stream>>>(ptsG, edgesG, contrib);
    final_kernel<<<1, 64, 0, stream>>>(contrib, out);
}

// Round 6
// 572.385 us; speedup vs baseline: 1.1458x; 1.1458x over previous
//
#include <hip/hip_runtime.h>

#define HH 512
#define WW 512
#define NPIX (HH * WW)          // 262144
#define NIMG 16
#define KPTS 1024
#define NWORDS (NPIX / 64)      // 4096 u64 mask words per image

// ---------------------------------------------------------------------------
// Kernel 1: binarize + uniform LBP (P=8,R=1) + ballot-pack mask bits
// ---------------------------------------------------------------------------
__global__ void lbp_kernel(const float* __restrict__ mo,
                           const float* __restrict__ lb,
                           unsigned long long* __restrict__ maskbits) {
#pragma clang fp contract(off)
    int m = blockIdx.y;                    // image 0..15: even=pred, odd=mask
    int pix = blockIdx.x * blockDim.x + threadIdx.x;   // 0..262143
    int r = pix >> 9, c = pix & 511;
    int sample = m >> 1;
    const float* img = (m & 1) ? (lb + sample * NPIX) : (mo + sample * NPIX);
    float thr = (m & 1) ? 0.5f : 0.0f;     // sigmoid(x)>0.5 <=> x>0

    float center = img[pix] > thr ? 1.0f : 0.0f;

    const float A = 0.70710678f;           // np.round(sin/cos, 8)
    const float drs[8] = {0.f, -A, -1.f, -A, 0.f,  A, 1.f, A};
    const float dcs[8] = {1.f,  A,  0.f, -A, -1.f, -A, 0.f, A};

    unsigned bb = 0u;
#pragma unroll
    for (int k = 0; k < 8; k++) {
        float rr = (float)r + drs[k];
        float cc = (float)c + dcs[k];
        float r0 = floorf(rr), c0 = floorf(cc);
        float fr = rr - r0,   fc = cc - c0;
        int r0i = (int)r0; r0i = max(0, min(HH - 1, r0i));
        int c0i = (int)c0; c0i = max(0, min(WW - 1, c0i));
        int r1i = min(HH - 1, r0i + 1);
        int c1i = min(WW - 1, c0i + 1);
        float g00 = img[r0i * WW + c0i] > thr ? 1.0f : 0.0f;
        float g01 = img[r0i * WW + c1i] > thr ? 1.0f : 0.0f;
        float g10 = img[r1i * WW + c0i] > thr ? 1.0f : 0.0f;
        float g11 = img[r1i * WW + c1i] > thr ? 1.0f : 0.0f;
        float s1 = (1.0f - fc) * g00 + fc * g01;
        float s2 = (1.0f - fc) * g10 + fc * g11;
        float smp = (1.0f - fr) * s1 + fr * s2;
        if (smp - center >= 0.0f) bb |= (1u << k);
    }
    unsigned rol = ((bb << 1) | (bb >> 7)) & 0xFFu;
    int changes = __popc(bb ^ rol);
    int s = __popc(bb);
    bool maskbit = (changes <= 2) && (s < 5);   // lbp < THR(=5)

    unsigned long long w = __ballot(maskbit);
    if ((threadIdx.x & 63) == 0)
        maskbits[m * NWORDS + (pix >> 6)] = w;
}

// ---------------------------------------------------------------------------
// Kernel 2: stable row-major compaction to K=1024 packed points per image
// pts entry: (r<<16)|c ; zero-padded. Shfl scan + uniform early-exit once
// K points are found (random inputs -> chunk 0 already has ~2x K).
// ---------------------------------------------------------------------------
__global__ void select_kernel(const unsigned long long* __restrict__ maskbits,
                              unsigned* __restrict__ ptsG) {
    __shared__ unsigned swv[4];
    int m = blockIdx.x, tid = threadIdx.x;
    int lane = tid & 63, wid = tid >> 6;

    for (int i = tid; i < KPTS; i += 256) ptsG[m * KPTS + i] = 0u;
    __syncthreads();

    unsigned running = 0;
    for (int ch = 0; ch < 16; ch++) {
        int w = ch * 256 + tid;
        unsigned long long word = maskbits[m * NWORDS + w];
        unsigned cnt = (unsigned)__popcll(word);

        unsigned x = cnt;                    // intra-wave inclusive scan
#pragma unroll
        for (int d = 1; d < 64; d <<= 1) {
            unsigned y = (unsigned)__shfl_up((int)x, d, 64);
            x += (lane >= d) ? y : 0u;
        }
        if (lane == 63) swv[wid] = x;
        __syncthreads();
        unsigned woff = 0, total = 0;
#pragma unroll
        for (int ww = 0; ww < 4; ww++) {
            unsigned t = swv[ww];
            total += t;
            woff += (ww < wid) ? t : 0u;
        }
        unsigned rank = running + woff + x - cnt;   // exclusive prefix
        while (word) {
            int b = __builtin_ctzll(word);
            word &= word - 1;
            if (rank < (unsigned)KPTS) {
                unsigned p = (unsigned)(w * 64 + b);
                unsigned rr = p >> 9, cc = p & 511u;
                ptsG[m * KPTS + rank] = (rr << 16) | cc;
            }
            rank++;
        }
        running += total;
        if (running >= (unsigned)KPTS) break;   // uniform -> safe
        __syncthreads();   // protect swv before next chunk
    }
}

// ---------------------------------------------------------------------------
// Kernel 3 (phase 1): single-wave Prim per image, RECORD-ONLY, ZERO LDS.
// State = 48 NAMED scalars pinned into arch VGPRs via empty asm each
// iteration (defeats remat-from-global which caused R4/R5's ~1000cyc/iter).
// key = (d2<<10)|idx : unsigned-min == argmin w/ first-index ties;
// in-tree key = 0xFFFFFFFF (signed -1 so update '<' never wins).
// ---------------------------------------------------------------------------
typedef short v2s __attribute__((ext_vector_type(2)));

__device__ __forceinline__ int dist2_packed(unsigned a, unsigned b) {
#if __has_builtin(__builtin_amdgcn_sdot2)
    v2s d = __builtin_bit_cast(v2s, a) - __builtin_bit_cast(v2s, b);
    return __builtin_amdgcn_sdot2(d, d, 0, false);
#else
    int dr = (int)(a >> 16) - (int)(b >> 16);
    int dc = (int)(a & 0xFFFFu) - (int)(b & 0xFFFFu);
    return __mul24(dr, dr) + __mul24(dc, dc);
#endif
}

template <int CTRL>
__device__ __forceinline__ unsigned umin_dpp(unsigned x) {
    unsigned o = (unsigned)__builtin_amdgcn_update_dpp((int)x, (int)x, CTRL,
                                                       0xf, 0xf, false);
    return o < x ? o : x;
}

__device__ __forceinline__ unsigned umin3(unsigned a, unsigned b, unsigned c) {
    unsigned t = a < b ? a : b;          // fuses to v_min3_u32
    return t < c ? t : c;
}

#define SLOT_INIT(s, ps, ks, is)                                          \
    is = (unsigned)((s << 6) | lane);                                     \
    ps = base[(s << 6) | lane];                                           \
    { int _d2 = dist2_packed(ps, pt0);                                    \
      ks = ((unsigned)_d2 << 10) | is; }

#define SLOT_UPD(s, ps, ks, is)                                           \
    { v2s _d = __builtin_bit_cast(v2s, ps) - pj2;                         \
      int _d2;                                                            \
      _d2 = __builtin_amdgcn_sdot2(_d, _d, 0, false);                     \
      unsigned _nk = ((unsigned)_d2 << 10) | is;                          \
      ks = ((int)_nk < (int)ks) ? _nk : ks;                               \
      ks = (hit && (wslot == (s))) ? 0xFFFFFFFFu : ks; }

#define INLANE_MIN16(res)                                                 \
    { unsigned _m0 = umin3(k0, k1, k2);                                   \
      unsigned _m1 = umin3(k3, k4, k5);                                   \
      unsigned _m2 = umin3(k6, k7, k8);                                   \
      unsigned _m3 = umin3(k9, k10, k11);                                 \
      unsigned _m4 = umin3(k12, k13, k14);                                \
      unsigned _ra = umin3(_m0, _m1, _m2);                                \
      unsigned _rb = umin3(_m3, _m4, k15);                                \
      res = _ra < _rb ? _ra : _rb; }

#define SEL16P(res)                                                       \
    { unsigned _a0 = b0 ? p1  : p0;                                       \
      unsigned _a1 = b0 ? p3  : p2;                                       \
      unsigned _a2 = b0 ? p5  : p4;                                       \
      unsigned _a3 = b0 ? p7  : p6;                                       \
      unsigned _a4 = b0 ? p9  : p8;                                       \
      unsigned _a5 = b0 ? p11 : p10;                                      \
      unsigned _a6 = b0 ? p13 : p12;                                      \
      unsigned _a7 = b0 ? p15 : p14;                                      \
      unsigned _c0 = b1 ? _a1 : _a0;                                      \
      unsigned _c1 = b1 ? _a3 : _a2;                                      \
      unsigned _c2 = b1 ? _a5 : _a4;                                      \
      unsigned _c3 = b1 ? _a7 : _a6;                                      \
      unsigned _e0 = b2 ? _c1 : _c0;                                      \
      unsigned _e1 = b2 ? _c3 : _c2;                                      \
      res = b3 ? _e1 : _e0; }

__global__ __launch_bounds__(64, 1) void mst_kernel(const unsigned* __restrict__ ptsG,
                                                    unsigned* __restrict__ edgesG) {
    int lane = threadIdx.x;          // 0..63
    int m = blockIdx.x;
    const unsigned* base = ptsG + m * KPTS;
    unsigned pt0 = base[0];          // self point 0 (uniform s_load)

    unsigned k0,k1,k2,k3,k4,k5,k6,k7,k8,k9,k10,k11,k12,k13,k14,k15;
    unsigned p0,p1,p2,p3,p4,p5,p6,p7,p8,p9,p10,p11,p12,p13,p14,p15;
    unsigned i0,i1,i2,i3,i4,i5,i6,i7,i8,i9,i10,i11,i12,i13,i14,i15;

    SLOT_INIT(0,  p0,  k0,  i0);   SLOT_INIT(1,  p1,  k1,  i1);
    SLOT_INIT(2,  p2,  k2,  i2);   SLOT_INIT(3,  p3,  k3,  i3);
    SLOT_INIT(4,  p4,  k4,  i4);   SLOT_INIT(5,  p5,  k5,  i5);
    SLOT_INIT(6,  p6,  k6,  i6);   SLOT_INIT(7,  p7,  k7,  i7);
    SLOT_INIT(8,  p8,  k8,  i8);   SLOT_INIT(9,  p9,  k9,  i9);
    SLOT_INIT(10, p10, k10, i10);  SLOT_INIT(11, p11, k11, i11);
    SLOT_INIT(12, p12, k12, i12);  SLOT_INIT(13, p13, k13, i13);
    SLOT_INIT(14, p14, k14, i14);  SLOT_INIT(15, p15, k15, i15);

    k0 = (lane == 0) ? 0xFFFFFFFFu : k0;   // in_tree[0] = True

    unsigned* eout = edgesG + m * KPTS;
    unsigned rk;
    INLANE_MIN16(rk);

    for (int it = 0; it < KPTS - 1; it++) {
        // pin state into arch VGPRs: compiler may not remat from memory
        asm volatile("" : "+v"(p0), "+v"(p1), "+v"(p2),  "+v"(p3),
                          "+v"(p4), "+v"(p5), "+v"(p6),  "+v"(p7),
                          "+v"(p8), "+v"(p9), "+v"(p10), "+v"(p11),
                          "+v"(p12), "+v"(p13), "+v"(p14), "+v"(p15));
        asm volatile("" : "+v"(k0), "+v"(k1), "+v"(k2),  "+v"(k3),
                          "+v"(k4), "+v"(k5), "+v"(k6),  "+v"(k7),
                          "+v"(k8), "+v"(k9), "+v"(k10), "+v"(k11),
                          "+v"(k12), "+v"(k13), "+v"(k14), "+v"(k15));
        asm volatile("" : "+v"(i0), "+v"(i1), "+v"(i2),  "+v"(i3),
                          "+v"(i4), "+v"(i5), "+v"(i6),  "+v"(i7),
                          "+v"(i8), "+v"(i9), "+v"(i10), "+v"(i11),
                          "+v"(i12), "+v"(i13), "+v"(i14), "+v"(i15));

        // ---- wave-64 min: 4 DPP row-folds + 4 readlane + scalar min ----
        rk = umin_dpp<0x111>(rk);   // row_shr:1
        rk = umin_dpp<0x112>(rk);   // row_shr:2
        rk = umin_dpp<0x114>(rk);   // row_shr:4
        rk = umin_dpp<0x118>(rk);   // row_shr:8 -> lane15 of each 16-row
        unsigned q0 = (unsigned)__builtin_amdgcn_readlane((int)rk, 15);
        unsigned q1 = (unsigned)__builtin_amdgcn_readlane((int)rk, 31);
        unsigned q2 = (unsigned)__builtin_amdgcn_readlane((int)rk, 47);
        unsigned q3 = (unsigned)__builtin_amdgcn_readlane((int)rk, 63);
        unsigned wa = q0 < q1 ? q0 : q1;
        unsigned wb = q2 < q3 ? q2 : q3;
        unsigned wk = wa < wb ? wa : wb;     // scalar, uniform

        unsigned j = wk & 1023u;
        int wslot = (int)(j >> 6);
        int wlane = (int)(j & 63u);

        if (lane == 0) eout[it] = wk;        // record edge (fire-and-forget)

        // ---- pj from the register file: SEL16 tree + readlane ----
        bool b0 = (wslot & 1) != 0, b1 = (wslot & 2) != 0;
        bool b2 = (wslot & 4) != 0, b3 = (wslot & 8) != 0;
        unsigned selPay;
        SEL16P(selPay);
        unsigned pjp = (unsigned)__builtin_amdgcn_readlane((int)selPay, wlane);
        v2s pj2 = __builtin_bit_cast(v2s, pjp);

        bool hit = (lane == wlane);

        // ---- decrease-key + remove j (branchless) ----
        SLOT_UPD(0,  p0,  k0,  i0);   SLOT_UPD(1,  p1,  k1,  i1);
        SLOT_UPD(2,  p2,  k2,  i2);   SLOT_UPD(3,  p3,  k3,  i3);
        SLOT_UPD(4,  p4,  k4,  i4);   SLOT_UPD(5,  p5,  k5,  i5);
        SLOT_UPD(6,  p6,  k6,  i6);   SLOT_UPD(7,  p7,  k7,  i7);
        SLOT_UPD(8,  p8,  k8,  i8);   SLOT_UPD(9,  p9,  k9,  i9);
        SLOT_UPD(10, p10, k10, i10);  SLOT_UPD(11, p11, k11, i11);
        SLOT_UPD(12, p12, k12, i12);  SLOT_UPD(13, p13, k13, i13);
        SLOT_UPD(14, p14, k14, i14);  SLOT_UPD(15, p15, k15, i15);

        INLANE_MIN16(rk);                    // next iteration's per-lane min
    }
}

// ---------------------------------------------------------------------------
// Kernel 4 (phase 2): recover src per edge + per-edge (Dp-Dm)^2.
// src[j] = earliest-extracted v with d2(v,j)==d2p (exact-int match) —
// provably identical to the reference's strict-'<' update history.
// ---------------------------------------------------------------------------
__global__ void recover_kernel(const unsigned* __restrict__ ptsG,
                               const unsigned* __restrict__ edgesG,
                               float* __restrict__ contrib) {
    __shared__ unsigned sS[KPTS];
    __shared__ unsigned sO[KPTS];
    __shared__ unsigned short sT[KPTS];   // extraction time + 1 (0 = root)
    int g = blockIdx.x, m = blockIdx.y;
    int tid = threadIdx.x;
    int partner = m ^ 1;

    for (int i = tid; i < KPTS; i += 256) {
        sS[i] = ptsG[m * KPTS + i];
        sO[i] = ptsG[partner * KPTS + i];
    }
    for (int e = tid; e < KPTS - 1; e += 256) {
        unsigned wkk = edgesG[m * KPTS + e];
        sT[wkk & 1023u] = (unsigned short)(e + 1);
    }
    if (tid == 0) sT[0] = 0;
    __syncthreads();

    int lane = tid & 63, w = tid >> 6;
    for (int k = 0; k < 16; k++) {
        int e = g * 64 + w * 16 + k;
        if (e >= KPTS - 1) break;            // only e=1023 (g=15,w=3,k=15)
        unsigned wk = edgesG[m * KPTS + e];
        unsigned j = wk & 1023u;
        unsigned d2p = wk >> 10;
        unsigned pj = sS[j];
        unsigned te1 = (unsigned)(e + 1);

        unsigned best = 0xFFFFFFFFu;
#pragma unroll
        for (int i = 0; i < 16; i++) {
            int v = i * 64 + lane;
            unsigned pv = sS[v];
            int d2 = dist2_packed(pv, pj);
            unsigned tv1 = (unsigned)sT[v];
            bool qual = ((unsigned)d2 == d2p) && (tv1 < te1);
            unsigned cand = qual ? ((tv1 << 10) | (unsigned)v) : 0xFFFFFFFFu;
            best = cand < best ? cand : best;
        }
#pragma unroll
        for (int dd = 32; dd; dd >>= 1) {
            unsigned o = (unsigned)__shfl_xor((int)best, dd, 64);
            best = o < best ? o : best;
        }
        unsigned vsrc = best & 1023u;
        if (lane == 0) {
            unsigned oj = sO[j], os = sO[vsrc];
            float Dp = __fsqrt_rn((float)d2p);
            float Dm = __fsqrt_rn((float)dist2_packed(oj, os));
            float diff = Dp - Dm;
            contrib[m * (KPTS - 1) + e] = diff * diff;
        }
    }
}

// ---------------------------------------------------------------------------
// Kernel 5: per-image f64 sum (extraction order, deterministic) -> loss
// ---------------------------------------------------------------------------
__global__ void final_kernel(const float* __restrict__ contrib,
                             float* __restrict__ out) {
    __shared__ double part[NIMG];
    int t = threadIdx.x;
    if (t < NIMG) {
        double s = 0.0;
        for (int e = 0; e < KPTS - 1; e++)
            s += (double)contrib[t * (KPTS - 1) + e];
        part[t] = sqrt(s);
    }
    __syncthreads();
    if (t == 0) {
        double tot = 0.0;
        for (int i = 0; i < NIMG; i++) tot += part[i];
        out[0] = (float)(0.1 * tot / 8.0);
    }
}

// ---------------------------------------------------------------------------
// ws layout:
//   [0,512K)     maskbits (lbp->select), then DEAD:
//   [0,64K)      edgesG   (mst->recover)   — overlaps dead maskbits
//   [64K,128K)   contrib  (recover->final) — overlaps dead maskbits
//   [512K,576K)  ptsG     (select->mst/recover)
// ---------------------------------------------------------------------------
extern "C" void kernel_launch(void* const* d_in, const int* in_sizes, int n_in,
                              void* d_out, int out_size, void* d_ws, size_t ws_size,
                              hipStream_t stream) {
    const float* mo = (const float*)d_in[1];   // model_output
    const float* lb = (const float*)d_in[2];   // labels

    unsigned long long* maskbits = (unsigned long long*)d_ws;
    unsigned* edgesG = (unsigned*)d_ws;
    float* contrib = (float*)((char*)d_ws + (size_t)64 * 1024);
    unsigned* ptsG = (unsigned*)((char*)d_ws + (size_t)NIMG * NWORDS * 8);
    float* out = (float*)d_out;

    lbp_kernel<<<dim3(NPIX / 256, NIMG), 256, 0, stream>>>(mo, lb, maskbits);
    select_kernel<<<NIMG, 256, 0, stream>>>(maskbits, ptsG);
    mst_kernel<<<NIMG, 64, 0, stream>>>(ptsG, edgesG);
    recover_kernel<<<dim3(16, NIMG), 256, 0, stream>>>(ptsG, edgesG, contrib);
    final_kernel<<<1, 64, 0, stream>>>(contrib, out);
}